// Round 2
// baseline (489.807 us; speedup 1.0000x reference)
//
#include <hip/hip_runtime.h>

typedef __attribute__((ext_vector_type(8)))  short short8;
typedef __attribute__((ext_vector_type(4)))  short short4v;
typedef __attribute__((ext_vector_type(4)))  float f32x4;
typedef __attribute__((ext_vector_type(16))) float f32x16;

__device__ inline short f2bf(float f) {
  unsigned u = __float_as_uint(f);
  u += 0x7fffu + ((u >> 16) & 1u);   // RNE to bf16
  return (short)(u >> 16);
}

// ---------------- fp32 -> bf16 weight conversion ----------------
__global__ void cvt_kernel(const float* __restrict__ in, short* __restrict__ out, int n4) {
  int i = blockIdx.x * blockDim.x + threadIdx.x;
  int stride = gridDim.x * blockDim.x;
  for (; i < n4; i += stride) {
    f32x4 v = ((const f32x4*)in)[i];
    short4v o;
    o[0] = f2bf(v[0]); o[1] = f2bf(v[1]); o[2] = f2bf(v[2]); o[3] = f2bf(v[3]);
    ((short4v*)out)[i] = o;
  }
}

// ---------------- stage 1: out1[b,k,q] = sum_p x[b,k*256+p] * w1[k,q,p] ----------------
// writes shuffled bf16 intermediate: inter[b][l][r], l = q&15, r = k*16 + (q>>4)
__global__ __launch_bounds__(256) void stage1_kernel(
    const float* __restrict__ x, const short* __restrict__ w1b, short* __restrict__ inter) {
  const int lane = threadIdx.x & 63;
  const int wq   = threadIdx.x >> 6;    // wave 0..3 -> q range
  const int b0   = blockIdx.x * 64;
  const int k    = blockIdx.y;          // 0..15
  const int q0w  = wq * 64;
  const int lr   = lane & 15;
  const int kid  = lane >> 4;           // 0..3

  f32x4 acc[4][4] = {};
  const float* xbase = x   + (size_t)(b0 + lr) * 4096 + k * 256 + kid * 8;
  const short* wbase = w1b + k * 65536 + (q0w + lr) * 256 + kid * 8;

  #pragma unroll
  for (int kk = 0; kk < 256; kk += 32) {
    short8 a[4], b[4];
    #pragma unroll
    for (int mt = 0; mt < 4; ++mt) {
      const f32x4* ap = (const f32x4*)(xbase + (size_t)mt * 16 * 4096 + kk);
      f32x4 lo = ap[0], hi = ap[1];
      short8 av;
      av[0] = f2bf(lo[0]); av[1] = f2bf(lo[1]); av[2] = f2bf(lo[2]); av[3] = f2bf(lo[3]);
      av[4] = f2bf(hi[0]); av[5] = f2bf(hi[1]); av[6] = f2bf(hi[2]); av[7] = f2bf(hi[3]);
      a[mt] = av;
    }
    #pragma unroll
    for (int nt = 0; nt < 4; ++nt)
      b[nt] = *(const short8*)(wbase + nt * 16 * 256 + kk);
    #pragma unroll
    for (int mt = 0; mt < 4; ++mt)
      #pragma unroll
      for (int nt = 0; nt < 4; ++nt)
        acc[mt][nt] = __builtin_amdgcn_mfma_f32_16x16x32_bf16(a[mt], b[nt], acc[mt][nt], 0, 0, 0);
  }

  // shuffled store: lane col c -> l = c ; r = k*16 + wq*4 + nt (4 r-contiguous -> 8B store)
  const int c = lr;
  const int rbase = k * 16 + wq * 4;
  #pragma unroll
  for (int mt = 0; mt < 4; ++mt) {
    #pragma unroll
    for (int j = 0; j < 4; ++j) {
      int brow = b0 + mt * 16 + kid * 4 + j;     // C/D: row = (lane>>4)*4 + reg
      short4v v;
      #pragma unroll
      for (int nt = 0; nt < 4; ++nt) v[nt] = f2bf(acc[mt][nt][j]);
      *(short4v*)(inter + (size_t)brow * 4096 + c * 256 + rbase) = v;
    }
  }
}

// ---------------- stage 2 (LDS-free): out[b][s*16+l] = sum_r inter[b][l][r] * w2[l][s][r] ----
// 32x32x16 MFMA, direct global fragment loads (both operands r-contiguous; each 64B line
// = one 32-r chunk, reused by kh=0/1 and both lane-halves -> L1 served). No barriers.
// Wave tile: 32b x 32s x 4l. acc=64 VGPR, frags=64 -> ~3 waves/SIMD, 16 loads in flight.
__global__ __launch_bounds__(256, 3) void stage2_kernel(
    const short* __restrict__ inter, const short* __restrict__ w2b, float* __restrict__ out) {
  const int lane = threadIdx.x & 63;
  const int wid  = threadIdx.x >> 6;
  const int wb   = wid >> 1;            // wave-grid 2x2
  const int ws   = wid & 1;
  int bx = blockIdx.x;
  bx = (bx & 7) * 8 + (bx >> 3);        // XCD-chunked b-tile swizzle (64 tiles, 8/XCD)
  const int b0    = bx * 64 + wb * 32;
  const int s0    = blockIdx.y * 64 + ws * 32;
  const int lbase = blockIdx.z * 4;     // l-quarter
  const int lrow  = lane & 31;
  const int khalf = lane >> 5;          // 0/1 -> which 8 of K=16

  const short* abase = inter + (size_t)(b0 + lrow) * 4096 + lbase * 256 + khalf * 8;
  const short* bbase = w2b + (size_t)lbase * 262144 + (size_t)(s0 + lrow) * 256 + khalf * 8;

  f32x16 acc[4] = {};

  #pragma unroll
  for (int ck = 0; ck < 8; ++ck) {
    short8 fa[8], fb[8];
    #pragma unroll
    for (int l = 0; l < 4; ++l) {
      #pragma unroll
      for (int kh = 0; kh < 2; ++kh) {
        int roff = ck * 32 + kh * 16;
        fa[l * 2 + kh] = *(const short8*)(abase + l * 256 + roff);
        fb[l * 2 + kh] = *(const short8*)(bbase + (size_t)l * 262144 + roff);
      }
    }
    #pragma unroll
    for (int l = 0; l < 4; ++l)
      #pragma unroll
      for (int kh = 0; kh < 2; ++kh)
        acc[l] = __builtin_amdgcn_mfma_f32_32x32x16_bf16(fa[l * 2 + kh], fb[l * 2 + kh],
                                                         acc[l], 0, 0, 0);
  }

  // epilogue: per (b,s) one lane owns 4 consecutive l -> dense f32x4 store
  const int colbase = (s0 + lrow) * 16 + lbase;
  #pragma unroll
  for (int reg = 0; reg < 16; ++reg) {
    int row = b0 + (reg & 3) + 8 * (reg >> 2) + 4 * khalf;  // verified 32x32 C/D map
    f32x4 v = { acc[0][reg], acc[1][reg], acc[2][reg], acc[3][reg] };
    *(f32x4*)(out + (size_t)row * 16384 + colbase) = v;
  }
}

extern "C" void kernel_launch(void* const* d_in, const int* in_sizes, int n_in,
                              void* d_out, int out_size, void* d_ws, size_t ws_size,
                              hipStream_t stream) {
  const float* x  = (const float*)d_in[0];
  const float* w1 = (const float*)d_in[1];
  const float* w2 = (const float*)d_in[2];
  float* out = (float*)d_out;

  short* inter = (short*)d_ws;                          // 32 MB  (4096 x 16 x 256 bf16)
  short* w1b   = (short*)((char*)d_ws + (32u << 20));   //  2 MB
  short* w2b   = (short*)((char*)d_ws + (34u << 20));   //  8 MB

  cvt_kernel<<<256, 256, 0, stream>>>(w1, w1b, 1048576 / 4);
  cvt_kernel<<<1024, 256, 0, stream>>>(w2, w2b, 4194304 / 4);
  stage1_kernel<<<dim3(64, 16), 256, 0, stream>>>(x, w1b, inter);
  stage2_kernel<<<dim3(64, 16, 4), 256, 0, stream>>>(inter, w2b, out);
}

// Round 3
// 436.770 us; speedup vs baseline: 1.1214x; 1.1214x over previous
//
#include <hip/hip_runtime.h>

typedef __attribute__((ext_vector_type(8)))  short short8;
typedef __attribute__((ext_vector_type(4)))  short short4v;
typedef __attribute__((ext_vector_type(4)))  float f32x4;
typedef __attribute__((ext_vector_type(16))) float f32x16;

__device__ inline short f2bf(float f) {
  unsigned u = __float_as_uint(f);
  u += 0x7fffu + ((u >> 16) & 1u);   // RNE to bf16
  return (short)(u >> 16);
}

// ---------------- fp32 -> bf16 weight conversion ----------------
__global__ void cvt_kernel(const float* __restrict__ in, short* __restrict__ out, int n4) {
  int i = blockIdx.x * blockDim.x + threadIdx.x;
  int stride = gridDim.x * blockDim.x;
  for (; i < n4; i += stride) {
    f32x4 v = ((const f32x4*)in)[i];
    short4v o;
    o[0] = f2bf(v[0]); o[1] = f2bf(v[1]); o[2] = f2bf(v[2]); o[3] = f2bf(v[3]);
    ((short4v*)out)[i] = o;
  }
}

// ---------------- stage 1: out1[b,k,q] = sum_p x[b,k*256+p] * w1[k,q,p] ----------------
// writes shuffled bf16 intermediate: inter[b][l][r], l = q&15, r = k*16 + (q>>4)
__global__ __launch_bounds__(256) void stage1_kernel(
    const float* __restrict__ x, const short* __restrict__ w1b, short* __restrict__ inter) {
  const int lane = threadIdx.x & 63;
  const int wq   = threadIdx.x >> 6;    // wave 0..3 -> q range
  const int b0   = blockIdx.x * 64;
  const int k    = blockIdx.y;          // 0..15
  const int q0w  = wq * 64;
  const int lr   = lane & 15;
  const int kid  = lane >> 4;           // 0..3

  f32x4 acc[4][4] = {};
  const float* xbase = x   + (size_t)(b0 + lr) * 4096 + k * 256 + kid * 8;
  const short* wbase = w1b + k * 65536 + (q0w + lr) * 256 + kid * 8;

  #pragma unroll
  for (int kk = 0; kk < 256; kk += 32) {
    short8 a[4], b[4];
    #pragma unroll
    for (int mt = 0; mt < 4; ++mt) {
      const f32x4* ap = (const f32x4*)(xbase + (size_t)mt * 16 * 4096 + kk);
      f32x4 lo = ap[0], hi = ap[1];
      short8 av;
      av[0] = f2bf(lo[0]); av[1] = f2bf(lo[1]); av[2] = f2bf(lo[2]); av[3] = f2bf(lo[3]);
      av[4] = f2bf(hi[0]); av[5] = f2bf(hi[1]); av[6] = f2bf(hi[2]); av[7] = f2bf(hi[3]);
      a[mt] = av;
    }
    #pragma unroll
    for (int nt = 0; nt < 4; ++nt)
      b[nt] = *(const short8*)(wbase + nt * 16 * 256 + kk);
    #pragma unroll
    for (int mt = 0; mt < 4; ++mt)
      #pragma unroll
      for (int nt = 0; nt < 4; ++nt)
        acc[mt][nt] = __builtin_amdgcn_mfma_f32_16x16x32_bf16(a[mt], b[nt], acc[mt][nt], 0, 0, 0);
  }

  // shuffled store: lane col c -> l = c ; r = k*16 + wq*4 + nt (4 r-contiguous -> 8B store)
  const int c = lr;
  const int rbase = k * 16 + wq * 4;
  #pragma unroll
  for (int mt = 0; mt < 4; ++mt) {
    #pragma unroll
    for (int j = 0; j < 4; ++j) {
      int brow = b0 + mt * 16 + kid * 4 + j;     // C/D: row = (lane>>4)*4 + reg
      short4v v;
      #pragma unroll
      for (int nt = 0; nt < 4; ++nt) v[nt] = f2bf(acc[mt][nt][j]);
      *(short4v*)(inter + (size_t)brow * 4096 + c * 256 + rbase) = v;
    }
  }
}

// ---------------- stage 2 (LDS-free, all-l blocks): ----------------
// out[b][s*16+l] = sum_r inter[b][l][r] * w2[l][s][r]
// Block = 4 waves = 4 l-quarters of the SAME 32b x 32s tile -> the four 16B
// pieces of each 64B output line come from one block (L2 write-merge).
// XCD-chunked decode: xcd owns an s-half (B-half 4MB, L2-resident) and a
// b-quarter; s varies fastest so each 256KB A-slice is reused by 16
// consecutive blocks on the same XCD.
__global__ __launch_bounds__(256) void stage2_kernel(
    const short* __restrict__ inter, const short* __restrict__ w2b, float* __restrict__ out) {
  const int lane  = threadIdx.x & 63;
  const int wid   = threadIdx.x >> 6;   // l-quarter
  const int lbase = wid * 4;
  const int lrow  = lane & 31;
  const int khalf = lane >> 5;          // 0/1 -> which 8 of K=16

  const int L    = blockIdx.x;          // 0..4095
  const int xcd  = L & 7;
  const int pos  = L >> 3;              // 0..511
  const int sh   = xcd & 1;             // s-half
  const int bg   = xcd >> 1;            // b-quarter 0..3
  const int s0   = ((pos & 15) + sh * 16) * 32;
  const int b0   = (bg * 32 + (pos >> 4)) * 32;

  const short* abase = inter + (size_t)(b0 + lrow) * 4096 + lbase * 256 + khalf * 8;
  const short* bbase = w2b + (size_t)lbase * 262144 + (size_t)(s0 + lrow) * 256 + khalf * 8;

  f32x16 acc[4] = {};

  #pragma unroll
  for (int ck = 0; ck < 8; ++ck) {
    short8 fa[8], fb[8];
    #pragma unroll
    for (int l = 0; l < 4; ++l) {
      #pragma unroll
      for (int kh = 0; kh < 2; ++kh) {
        int roff = ck * 32 + kh * 16;
        fa[l * 2 + kh] = *(const short8*)(abase + l * 256 + roff);
        fb[l * 2 + kh] = *(const short8*)(bbase + (size_t)l * 262144 + roff);
      }
    }
    #pragma unroll
    for (int l = 0; l < 4; ++l)
      #pragma unroll
      for (int kh = 0; kh < 2; ++kh)
        acc[l] = __builtin_amdgcn_mfma_f32_32x32x16_bf16(fa[l * 2 + kh], fb[l * 2 + kh],
                                                         acc[l], 0, 0, 0);
  }

  // epilogue: per (b,s) one lane owns 4 consecutive l -> dense f32x4 store;
  // 4 waves of this block fill the rest of each 64B line.
  const int colbase = (s0 + lrow) * 16 + lbase;
  #pragma unroll
  for (int reg = 0; reg < 16; ++reg) {
    int row = b0 + (reg & 3) + 8 * (reg >> 2) + 4 * khalf;  // verified 32x32 C/D map
    f32x4 v = { acc[0][reg], acc[1][reg], acc[2][reg], acc[3][reg] };
    *(f32x4*)(out + (size_t)row * 16384 + colbase) = v;
  }
}

extern "C" void kernel_launch(void* const* d_in, const int* in_sizes, int n_in,
                              void* d_out, int out_size, void* d_ws, size_t ws_size,
                              hipStream_t stream) {
  const float* x  = (const float*)d_in[0];
  const float* w1 = (const float*)d_in[1];
  const float* w2 = (const float*)d_in[2];
  float* out = (float*)d_out;

  short* inter = (short*)d_ws;                          // 32 MB  (4096 x 16 x 256 bf16)
  short* w1b   = (short*)((char*)d_ws + (32u << 20));   //  2 MB
  short* w2b   = (short*)((char*)d_ws + (34u << 20));   //  8 MB

  cvt_kernel<<<256, 256, 0, stream>>>(w1, w1b, 1048576 / 4);
  cvt_kernel<<<1024, 256, 0, stream>>>(w2, w2b, 4194304 / 4);
  stage1_kernel<<<dim3(64, 16), 256, 0, stream>>>(x, w1b, inter);
  stage2_kernel<<<4096, 256, 0, stream>>>(inter, w2b, out);
}

// Round 4
// 250.342 us; speedup vs baseline: 1.9565x; 1.7447x over previous
//
#include <hip/hip_runtime.h>

typedef __attribute__((ext_vector_type(8)))  short short8;
typedef __attribute__((ext_vector_type(4)))  short short4v;
typedef __attribute__((ext_vector_type(4)))  float f32x4;
typedef __attribute__((ext_vector_type(16))) float f32x16;

__device__ inline short f2bf(float f) {
  unsigned u = __float_as_uint(f);
  u += 0x7fffu + ((u >> 16) & 1u);   // RNE to bf16
  return (short)(u >> 16);
}

// ---------------- fp32 -> bf16 (w1, layout unchanged) ----------------
__global__ void cvt_kernel(const float* __restrict__ in, short* __restrict__ out, int n4) {
  int i = blockIdx.x * blockDim.x + threadIdx.x;
  int stride = gridDim.x * blockDim.x;
  for (; i < n4; i += stride) {
    f32x4 v = ((const f32x4*)in)[i];
    short4v o;
    o[0] = f2bf(v[0]); o[1] = f2bf(v[1]); o[2] = f2bf(v[2]); o[3] = f2bf(v[3]);
    ((short4v*)out)[i] = o;
  }
}

// ---------------- w2 fp32 -> bf16 fragment-major ----------------
// w2f[l][stile][ck][kh][lane][8] ; lane=(khalf<<5)|lrow ; s=stile*32+lrow ;
// r = ck*32 + kh*16 + khalf*8. One thread = one fragment-lane (8 shorts).
__global__ void cvt_w2_frag(const float* __restrict__ w2, short* __restrict__ w2f) {
  int t = blockIdx.x * 256 + threadIdx.x;        // 0 .. 524287
  int lane  = t & 63;
  int f     = t >> 6;
  int kh    = f & 1;
  int ck    = (f >> 1) & 7;
  int stile = (f >> 4) & 31;
  int l     = f >> 9;
  int lrow = lane & 31, khalf = lane >> 5;
  int s = stile * 32 + lrow;
  int r = ck * 32 + kh * 16 + khalf * 8;
  const float* src = w2 + (size_t)(l * 1024 + s) * 256 + r;
  f32x4 lo = *(const f32x4*)src;
  f32x4 hi = *(const f32x4*)(src + 4);
  short8 o;
  o[0]=f2bf(lo[0]); o[1]=f2bf(lo[1]); o[2]=f2bf(lo[2]); o[3]=f2bf(lo[3]);
  o[4]=f2bf(hi[0]); o[5]=f2bf(hi[1]); o[6]=f2bf(hi[2]); o[7]=f2bf(hi[3]);
  ((short8*)w2f)[t] = o;
}

// ---------------- stage 1: out1[b,k,q] = sum_p x[b,k*256+p] * w1[k,q,p] ----------------
// Writes shuffled intermediate in A-fragment-major order:
// interf[btile(128)][l(16)][ck(8)][kh(2)][lane(64)][8]
// with l=q&15, r=k*16+(q>>4) -> ck=k>>1, kh=k&1, lane=(khalf<<5)|(brow&31),
// khalf=(r>>3)&1=wq>>1, e=r&7=(wq&1)*4+nt.
__global__ __launch_bounds__(256) void stage1_kernel(
    const float* __restrict__ x, const short* __restrict__ w1b, short* __restrict__ interf) {
  const int lane = threadIdx.x & 63;
  const int wq   = threadIdx.x >> 6;    // wave 0..3 -> q range
  const int b0   = blockIdx.x * 64;
  const int k    = blockIdx.y;          // 0..15
  const int q0w  = wq * 64;
  const int lr   = lane & 15;
  const int kid  = lane >> 4;           // 0..3

  f32x4 acc[4][4] = {};
  const float* xbase = x   + (size_t)(b0 + lr) * 4096 + k * 256 + kid * 8;
  const short* wbase = w1b + k * 65536 + (q0w + lr) * 256 + kid * 8;

  #pragma unroll
  for (int kk = 0; kk < 256; kk += 32) {
    short8 a[4], b[4];
    #pragma unroll
    for (int mt = 0; mt < 4; ++mt) {
      const f32x4* ap = (const f32x4*)(xbase + (size_t)mt * 16 * 4096 + kk);
      f32x4 lo = ap[0], hi = ap[1];
      short8 av;
      av[0] = f2bf(lo[0]); av[1] = f2bf(lo[1]); av[2] = f2bf(lo[2]); av[3] = f2bf(lo[3]);
      av[4] = f2bf(hi[0]); av[5] = f2bf(hi[1]); av[6] = f2bf(hi[2]); av[7] = f2bf(hi[3]);
      a[mt] = av;
    }
    #pragma unroll
    for (int nt = 0; nt < 4; ++nt)
      b[nt] = *(const short8*)(wbase + nt * 16 * 256 + kk);
    #pragma unroll
    for (int mt = 0; mt < 4; ++mt)
      #pragma unroll
      for (int nt = 0; nt < 4; ++nt)
        acc[mt][nt] = __builtin_amdgcn_mfma_f32_16x16x32_bf16(a[mt], b[nt], acc[mt][nt], 0, 0, 0);
  }

  const int ck = k >> 1, kh = k & 1;
  #pragma unroll
  for (int mt = 0; mt < 4; ++mt) {
    #pragma unroll
    for (int j = 0; j < 4; ++j) {
      int brow  = b0 + mt * 16 + kid * 4 + j;   // C/D: row = (lane>>4)*4 + reg
      int btile = brow >> 5;
      int lanep = ((wq >> 1) << 5) | (brow & 31);
      size_t off = (((((size_t)btile * 16 + lr) * 8 + ck) * 2 + kh) * 64 + lanep) * 8
                   + (wq & 1) * 4;
      short4v v;
      #pragma unroll
      for (int nt = 0; nt < 4; ++nt) v[nt] = f2bf(acc[mt][nt][j]);
      *(short4v*)(interf + off) = v;
    }
  }
}

// ---------------- stage 2 (fragment-major, fully coalesced loads) ----------------
// out[b][s*16+l] = sum_r inter[b][l][r] * w2[l][s][r]
// Block = 4 waves = 4 l-quarters of one 32b x 32s tile (write-merge intact).
// Every fragment load = one contiguous 1KB burst (lane*16B).
// XCD decode: xcd owns b-quarter x s-half; s-supertiles of 8 (B-group 2MB
// L2-resident, room left for streamed 256KB A-slices).
__global__ __launch_bounds__(256) void stage2_kernel(
    const short* __restrict__ interf, const short* __restrict__ w2f, float* __restrict__ out) {
  const int lane  = threadIdx.x & 63;
  const int wid   = threadIdx.x >> 6;   // l-quarter
  const int lbase = wid * 4;
  const int lrow  = lane & 31;
  const int khalf = lane >> 5;

  const int L    = blockIdx.x;          // 0..4095
  const int xcd  = L & 7;
  const int pos  = L >> 3;              // 0..511
  const int sh   = xcd & 1;
  const int bg   = xcd >> 1;
  const int ssg  = pos >> 8;            // s-supertile (2 per half)
  const int st   = pos & 7;             // s-tile in supertile (fastest)
  const int bsl  = (pos >> 3) & 31;     // b-subtile in quarter
  const int stile = sh * 16 + ssg * 8 + st;
  const int bsub  = bg * 32 + bsl;
  const int s0 = stile * 32;
  const int b0 = bsub * 32;

  // fragment strides (shorts): kh=512, ck=1024, l(A)=8192, l(B)=262144, stile=8192
  const short* abase = interf + (((size_t)bsub * 16 + lbase) * 8192) + lane * 8;
  const short* bbase = w2f + ((size_t)lbase * 262144 + (size_t)stile * 8192) + lane * 8;

  f32x16 acc[4] = {};

  #pragma unroll
  for (int ck = 0; ck < 8; ++ck) {
    short8 fa[8], fb[8];
    #pragma unroll
    for (int l = 0; l < 4; ++l) {
      #pragma unroll
      for (int kh = 0; kh < 2; ++kh) {
        fa[l * 2 + kh] = *(const short8*)(abase + l * 8192   + ck * 1024 + kh * 512);
        fb[l * 2 + kh] = *(const short8*)(bbase + l * 262144 + ck * 1024 + kh * 512);
      }
    }
    #pragma unroll
    for (int l = 0; l < 4; ++l)
      #pragma unroll
      for (int kh = 0; kh < 2; ++kh)
        acc[l] = __builtin_amdgcn_mfma_f32_32x32x16_bf16(fa[l * 2 + kh], fb[l * 2 + kh],
                                                         acc[l], 0, 0, 0);
  }

  // epilogue: per (b,s) one lane owns 4 consecutive l -> dense f32x4 store;
  // the block's 4 waves fill each 64B line.
  const int colbase = (s0 + lrow) * 16 + lbase;
  #pragma unroll
  for (int reg = 0; reg < 16; ++reg) {
    int row = b0 + (reg & 3) + 8 * (reg >> 2) + 4 * khalf;  // verified 32x32 C/D map
    f32x4 v = { acc[0][reg], acc[1][reg], acc[2][reg], acc[3][reg] };
    *(f32x4*)(out + (size_t)row * 16384 + colbase) = v;
  }
}

extern "C" void kernel_launch(void* const* d_in, const int* in_sizes, int n_in,
                              void* d_out, int out_size, void* d_ws, size_t ws_size,
                              hipStream_t stream) {
  const float* x  = (const float*)d_in[0];
  const float* w1 = (const float*)d_in[1];
  const float* w2 = (const float*)d_in[2];
  float* out = (float*)d_out;

  short* interf = (short*)d_ws;                          // 32 MB  (fragment-major)
  short* w1b    = (short*)((char*)d_ws + (32u << 20));   //  2 MB
  short* w2f    = (short*)((char*)d_ws + (34u << 20));   //  8 MB  (fragment-major)

  cvt_kernel<<<256, 256, 0, stream>>>(w1, w1b, 1048576 / 4);
  cvt_w2_frag<<<2048, 256, 0, stream>>>(w2, w2f);
  stage1_kernel<<<dim3(64, 16), 256, 0, stream>>>(x, w1b, interf);
  stage2_kernel<<<4096, 256, 0, stream>>>(interf, w2f, out);
}

// Round 5
// 179.483 us; speedup vs baseline: 2.7290x; 1.3948x over previous
//
#include <hip/hip_runtime.h>

typedef __attribute__((ext_vector_type(8)))  short short8;
typedef __attribute__((ext_vector_type(4)))  short short4v;
typedef __attribute__((ext_vector_type(4)))  float f32x4;
typedef __attribute__((ext_vector_type(16))) float f32x16;

__device__ inline short f2bf(float f) {
  unsigned u = __float_as_uint(f);
  u += 0x7fffu + ((u >> 16) & 1u);   // RNE to bf16
  return (short)(u >> 16);
}

// ---------------- fp32 -> bf16 (w1, layout unchanged) ----------------
__global__ void cvt_kernel(const float* __restrict__ in, short* __restrict__ out, int n4) {
  int i = blockIdx.x * blockDim.x + threadIdx.x;
  int stride = gridDim.x * blockDim.x;
  for (; i < n4; i += stride) {
    f32x4 v = ((const f32x4*)in)[i];
    short4v o;
    o[0] = f2bf(v[0]); o[1] = f2bf(v[1]); o[2] = f2bf(v[2]); o[3] = f2bf(v[3]);
    ((short4v*)out)[i] = o;
  }
}

// ---------------- w2 fp32 -> bf16 fragment-major ----------------
// w2f[l][stile(32)][kstep(16)][lane(64)][8] ; lane=(khalf<<5)|srow ; s=stile*32+srow ;
// r = kstep*16 + khalf*8 + e.
__global__ void cvt_w2_frag(const float* __restrict__ w2, short* __restrict__ w2f) {
  int t = blockIdx.x * 256 + threadIdx.x;        // 0 .. 524287
  int lane  = t & 63;
  int f     = t >> 6;
  int kh    = f & 1;
  int ck    = (f >> 1) & 7;
  int stile = (f >> 4) & 31;
  int l     = f >> 9;
  int lrow = lane & 31, khalf = lane >> 5;
  int s = stile * 32 + lrow;
  int r = ck * 32 + kh * 16 + khalf * 8;
  const float* src = w2 + (size_t)(l * 1024 + s) * 256 + r;
  f32x4 lo = *(const f32x4*)src;
  f32x4 hi = *(const f32x4*)(src + 4);
  short8 o;
  o[0]=f2bf(lo[0]); o[1]=f2bf(lo[1]); o[2]=f2bf(lo[2]); o[3]=f2bf(lo[3]);
  o[4]=f2bf(hi[0]); o[5]=f2bf(hi[1]); o[6]=f2bf(hi[2]); o[7]=f2bf(hi[3]);
  ((short8*)w2f)[t] = o;
}

// ---------------- stage 1: out1[b,k,q] = sum_p x[b,k*256+p] * w1[k,q,p] ----------------
// Computes as R4, then transposes through LDS and stores the A-fragment-major
// intermediate with coalesced 1KB wave bursts:
// interf[btile(128)][l(16)][kstep(16)][lane(64)][8], kstep = k (ck*2+kh).
__global__ __launch_bounds__(256) void stage1_kernel(
    const float* __restrict__ x, const short* __restrict__ w1b, short* __restrict__ interf) {
  __shared__ short s1lds[16384];          // [blocal 64][l 16][rlocal 16], XOR-swizzled
  const int lane = threadIdx.x & 63;
  const int wq   = threadIdx.x >> 6;    // wave 0..3 -> q range
  const int b0   = blockIdx.x * 64;
  const int k    = blockIdx.y;          // 0..15
  const int q0w  = wq * 64;
  const int lr   = lane & 15;
  const int kid  = lane >> 4;           // 0..3

  f32x4 acc[4][4] = {};
  const float* xbase = x   + (size_t)(b0 + lr) * 4096 + k * 256 + kid * 8;
  const short* wbase = w1b + k * 65536 + (q0w + lr) * 256 + kid * 8;

  #pragma unroll
  for (int kk = 0; kk < 256; kk += 32) {
    short8 a[4], b[4];
    #pragma unroll
    for (int mt = 0; mt < 4; ++mt) {
      const f32x4* ap = (const f32x4*)(xbase + (size_t)mt * 16 * 4096 + kk);
      f32x4 lo = ap[0], hi = ap[1];
      short8 av;
      av[0] = f2bf(lo[0]); av[1] = f2bf(lo[1]); av[2] = f2bf(lo[2]); av[3] = f2bf(lo[3]);
      av[4] = f2bf(hi[0]); av[5] = f2bf(hi[1]); av[6] = f2bf(hi[2]); av[7] = f2bf(hi[3]);
      a[mt] = av;
    }
    #pragma unroll
    for (int nt = 0; nt < 4; ++nt)
      b[nt] = *(const short8*)(wbase + nt * 16 * 256 + kk);
    #pragma unroll
    for (int mt = 0; mt < 4; ++mt)
      #pragma unroll
      for (int nt = 0; nt < 4; ++nt)
        acc[mt][nt] = __builtin_amdgcn_mfma_f32_16x16x32_bf16(a[mt], b[nt], acc[mt][nt], 0, 0, 0);
  }

  // acc -> LDS transpose. value(b=blocal, q) with l=q&15=lr, rlocal=q>>4=wq*4+nt.
  #pragma unroll
  for (int mt = 0; mt < 4; ++mt) {
    #pragma unroll
    for (int j = 0; j < 4; ++j) {
      int blocal = mt * 16 + kid * 4 + j;            // row = (lane>>4)*4 + reg
      int byte = blocal * 512 + lr * 32 + wq * 8;
      byte ^= (blocal & 7) << 4;
      short4v v;
      #pragma unroll
      for (int nt = 0; nt < 4; ++nt) v[nt] = f2bf(acc[mt][nt][j]);
      *(short4v*)((char*)s1lds + byte) = v;
    }
  }
  __syncthreads();

  // fragment-major store: 8 iters x 4 waves = 32 frags of 1KB, fully coalesced
  const int brow = lane & 31, khalf = lane >> 5;
  #pragma unroll
  for (int j = 0; j < 8; ++j) {
    int f   = j * 4 + wq;
    int btl = f >> 4, l = f & 15;
    int blc = btl * 32 + brow;
    int rbyte = (blc * 512 + l * 32 + khalf * 16) ^ ((blc & 7) << 4);
    short8 v = *(const short8*)((char*)s1lds + rbyte);
    size_t off = (((size_t)(blockIdx.x * 2 + btl) * 16 + l) * 16 + k) * 512 + lane * 8;
    *(short8*)(interf + off) = v;
  }
}

// ---------------- stage 2: out[b][s*16+l] = sum_r inter[b][l][r] * w2[l][s][r] ----------------
// 1024 threads = 16 waves = 16 l; per wave: 64b x 64s tile (2x2 MFMA tiles, acc 64 VGPR).
// Per kstep: 4 coalesced 1KB frag loads feeding 4 MFMA (1:1), next-kstep prefetch.
// Epilogue: C transposed through 64KB LDS -> coalesced f32x4 stores, all 16 l per line.
__global__ __launch_bounds__(1024, 4) void stage2_kernel(
    const short* __restrict__ interf, const short* __restrict__ w2f, float* __restrict__ out) {
  __shared__ float clds[16 * 1024];      // 64KB C-transpose buffer
  const int tid  = threadIdx.x;
  const int lane = tid & 63;
  const int l    = tid >> 6;             // wave = l
  const int lrow = lane & 31;
  const int khalf = lane >> 5;

  // grid decode: xcd owns A-quarter (8 BBT); 4bt x 4st supertiles (A+B ~4MB L2-resident)
  const int L    = blockIdx.x;           // 0..1023
  const int xcd  = L & 7;
  const int pos  = L >> 3;               // 0..127
  const int sup  = pos >> 4;             // 0..7
  const int inner = pos & 15;
  const int BBT  = xcd * 8 + (sup & 1) * 4 + (inner & 3);   // 0..63 (64 b-rows each)
  const int BST  = (sup >> 1) * 4 + (inner >> 2);           // 0..15 (64 s each)
  const int b0 = BBT * 64, s0 = BST * 64;

  // interf[btile][l][kstep][lane][8]: btile stride 131072, l stride 8192, kstep 512
  const short* ap = interf + (size_t)(BBT * 2) * 131072 + l * 8192 + lane * 8;
  // w2f[l][stile][kstep][lane][8]: l stride 262144, stile 8192, kstep 512
  const short* bp = w2f + (size_t)l * 262144 + (size_t)(BST * 2) * 8192 + lane * 8;

  f32x16 acc[2][2] = {};

  short8 ca0 = *(const short8*)ap;
  short8 ca1 = *(const short8*)(ap + 131072);
  short8 cb0 = *(const short8*)bp;
  short8 cb1 = *(const short8*)(bp + 8192);
  #pragma unroll
  for (int ks = 0; ks < 16; ++ks) {
    short8 na0 = ca0, na1 = ca1, nb0 = cb0, nb1 = cb1;
    if (ks < 15) {
      na0 = *(const short8*)(ap + (ks + 1) * 512);
      na1 = *(const short8*)(ap + 131072 + (ks + 1) * 512);
      nb0 = *(const short8*)(bp + (ks + 1) * 512);
      nb1 = *(const short8*)(bp + 8192 + (ks + 1) * 512);
    }
    acc[0][0] = __builtin_amdgcn_mfma_f32_32x32x16_bf16(ca0, cb0, acc[0][0], 0, 0, 0);
    acc[0][1] = __builtin_amdgcn_mfma_f32_32x32x16_bf16(ca0, cb1, acc[0][1], 0, 0, 0);
    acc[1][0] = __builtin_amdgcn_mfma_f32_32x32x16_bf16(ca1, cb0, acc[1][0], 0, 0, 0);
    acc[1][1] = __builtin_amdgcn_mfma_f32_32x32x16_bf16(ca1, cb1, acc[1][1], 0, 0, 0);
    ca0 = na0; ca1 = na1; cb0 = nb0; cb1 = nb1;
  }

  // epilogue: 4 chunks of 16 rows; LDS [row16][col'] f32, col = scol*16 + l,
  // swizzle l-slot: l ^= ((scol&3)<<2) ^ (((row16>>2)&3)<<2)  (keeps f32x4 groups intact)
  #pragma unroll
  for (int c = 0; c < 4; ++c) {
    const int bt = c >> 1, rh = c & 1;
    #pragma unroll
    for (int st = 0; st < 2; ++st) {
      int scol = st * 32 + lrow;
      #pragma unroll
      for (int rr = 0; rr < 8; ++rr) {
        int row16 = (rr & 3) + 8 * (rr >> 2) + 4 * khalf;   // verified 32x32 C/D map (mod 16)
        int colx = scol * 16 + (l ^ ((scol & 3) << 2) ^ (((row16 >> 2) & 3) << 2));
        clds[row16 * 1024 + colx] = acc[bt][st][rh * 8 + rr];
      }
    }
    __syncthreads();
    #pragma unroll
    for (int p = 0; p < 4; ++p) {
      int idx  = p * 1024 + tid;
      int row  = idx >> 8;                 // 0..15
      int slot = idx & 255;
      int scol = slot >> 2, lq = slot & 3;
      int colx = scol * 16 + ((lq * 4) ^ ((scol & 3) << 2) ^ (((row >> 2) & 3) << 2));
      f32x4 v = *(const f32x4*)&clds[row * 1024 + colx];
      *(f32x4*)(out + (size_t)(b0 + c * 16 + row) * 16384
                     + (size_t)(s0 + scol) * 16 + lq * 4) = v;
    }
    __syncthreads();
  }
}

extern "C" void kernel_launch(void* const* d_in, const int* in_sizes, int n_in,
                              void* d_out, int out_size, void* d_ws, size_t ws_size,
                              hipStream_t stream) {
  const float* x  = (const float*)d_in[0];
  const float* w1 = (const float*)d_in[1];
  const float* w2 = (const float*)d_in[2];
  float* out = (float*)d_out;

  short* interf = (short*)d_ws;                          // 32 MB  (fragment-major)
  short* w1b    = (short*)((char*)d_ws + (32u << 20));   //  2 MB
  short* w2f    = (short*)((char*)d_ws + (34u << 20));   //  8 MB  (fragment-major)

  cvt_kernel<<<256, 256, 0, stream>>>(w1, w1b, 1048576 / 4);
  cvt_w2_frag<<<2048, 256, 0, stream>>>(w2, w2f);
  stage1_kernel<<<dim3(64, 16), 256, 0, stream>>>(x, w1b, interf);
  stage2_kernel<<<1024, 1024, 0, stream>>>(interf, w2f, out);
}

// Round 7
// 176.833 us; speedup vs baseline: 2.7699x; 1.0150x over previous
//
#include <hip/hip_runtime.h>

typedef __attribute__((ext_vector_type(8)))  short short8;
typedef __attribute__((ext_vector_type(4)))  short short4v;
typedef __attribute__((ext_vector_type(4)))  float f32x4;
typedef __attribute__((ext_vector_type(16))) float f32x16;

__device__ inline short f2bf(float f) {
  unsigned u = __float_as_uint(f);
  u += 0x7fffu + ((u >> 16) & 1u);   // RNE to bf16
  return (short)(u >> 16);
}

// ---------------- fused weight conversion ----------------
// blocks [0,1024): w1 fp32->bf16 linear (2MB, one short4v per thread)
// blocks [1024,3072): w2 fp32->bf16 fragment-major:
//   w2f[l][stile(32)][kstep(16)][lane(64)][8]; lane=(khalf<<5)|srow;
//   s=stile*32+srow; r=kstep*16+khalf*8+e.
__global__ void cvt_all(const float* __restrict__ w1, short* __restrict__ w1b,
                        const float* __restrict__ w2, short* __restrict__ w2f) {
  if (blockIdx.x < 1024) {
    int i = blockIdx.x * 256 + threadIdx.x;          // covers n4 = 262144 exactly
    f32x4 v = ((const f32x4*)w1)[i];
    short4v o;
    o[0] = f2bf(v[0]); o[1] = f2bf(v[1]); o[2] = f2bf(v[2]); o[3] = f2bf(v[3]);
    ((short4v*)w1b)[i] = o;
    return;
  }
  int t = (blockIdx.x - 1024) * 256 + threadIdx.x;   // 0 .. 524287
  int lane  = t & 63;
  int f     = t >> 6;
  int kh    = f & 1;
  int ck    = (f >> 1) & 7;
  int stile = (f >> 4) & 31;
  int l     = f >> 9;
  int lrow = lane & 31, khalf = lane >> 5;
  int s = stile * 32 + lrow;
  int r = ck * 32 + kh * 16 + khalf * 8;
  const float* src = w2 + (size_t)(l * 1024 + s) * 256 + r;
  f32x4 lo = *(const f32x4*)src;
  f32x4 hi = *(const f32x4*)(src + 4);
  short8 o;
  o[0]=f2bf(lo[0]); o[1]=f2bf(lo[1]); o[2]=f2bf(lo[2]); o[3]=f2bf(lo[3]);
  o[4]=f2bf(hi[0]); o[5]=f2bf(hi[1]); o[6]=f2bf(hi[2]); o[7]=f2bf(hi[3]);
  ((short8*)w2f)[t] = o;
}

// ---------------- stage 1: out1[b,k,q] = sum_p x[b,k*256+p] * w1[k,q,p] ----------------
// Computes MFMA tiles, transposes through LDS, stores A-fragment-major:
// interf[btile(128)][l(16)][kstep(16)][lane(64)][8], kstep = k.
__global__ __launch_bounds__(256) void stage1_kernel(
    const float* __restrict__ x, const short* __restrict__ w1b, short* __restrict__ interf) {
  __shared__ short s1lds[16384];          // [blocal 64][l 16][rlocal 16], XOR-swizzled
  const int lane = threadIdx.x & 63;
  const int wq   = threadIdx.x >> 6;    // wave 0..3 -> q range
  const int b0   = blockIdx.x * 64;
  const int k    = blockIdx.y;          // 0..15
  const int q0w  = wq * 64;
  const int lr   = lane & 15;
  const int kid  = lane >> 4;           // 0..3

  f32x4 acc[4][4] = {};
  const float* xbase = x   + (size_t)(b0 + lr) * 4096 + k * 256 + kid * 8;
  const short* wbase = w1b + k * 65536 + (q0w + lr) * 256 + kid * 8;

  #pragma unroll
  for (int kk = 0; kk < 256; kk += 32) {
    short8 a[4], b[4];
    #pragma unroll
    for (int mt = 0; mt < 4; ++mt) {
      const f32x4* ap = (const f32x4*)(xbase + (size_t)mt * 16 * 4096 + kk);
      f32x4 lo = ap[0], hi = ap[1];
      short8 av;
      av[0] = f2bf(lo[0]); av[1] = f2bf(lo[1]); av[2] = f2bf(lo[2]); av[3] = f2bf(lo[3]);
      av[4] = f2bf(hi[0]); av[5] = f2bf(hi[1]); av[6] = f2bf(hi[2]); av[7] = f2bf(hi[3]);
      a[mt] = av;
    }
    #pragma unroll
    for (int nt = 0; nt < 4; ++nt)
      b[nt] = *(const short8*)(wbase + nt * 16 * 256 + kk);
    #pragma unroll
    for (int mt = 0; mt < 4; ++mt)
      #pragma unroll
      for (int nt = 0; nt < 4; ++nt)
        acc[mt][nt] = __builtin_amdgcn_mfma_f32_16x16x32_bf16(a[mt], b[nt], acc[mt][nt], 0, 0, 0);
  }

  // acc -> LDS transpose. value(b=blocal, q) with l=q&15=lr, rlocal=q>>4=wq*4+nt.
  #pragma unroll
  for (int mt = 0; mt < 4; ++mt) {
    #pragma unroll
    for (int j = 0; j < 4; ++j) {
      int blocal = mt * 16 + kid * 4 + j;            // row = (lane>>4)*4 + reg
      int byte = blocal * 512 + lr * 32 + wq * 8;
      byte ^= (blocal & 7) << 4;
      short4v v;
      #pragma unroll
      for (int nt = 0; nt < 4; ++nt) v[nt] = f2bf(acc[mt][nt][j]);
      *(short4v*)((char*)s1lds + byte) = v;
    }
  }
  __syncthreads();

  // fragment-major store: 8 iters x 4 waves = 32 frags of 1KB, fully coalesced
  const int brow = lane & 31, khalf = lane >> 5;
  #pragma unroll
  for (int j = 0; j < 8; ++j) {
    int f   = j * 4 + wq;
    int btl = f >> 4, l = f & 15;
    int blc = btl * 32 + brow;
    int rbyte = (blc * 512 + l * 32 + khalf * 16) ^ ((blc & 7) << 4);
    short8 v = *(const short8*)((char*)s1lds + rbyte);
    size_t off = (((size_t)(blockIdx.x * 2 + btl) * 16 + l) * 16 + k) * 512 + lane * 8;
    *(short8*)(interf + off) = v;
  }
}

// ---------------- stage 2: out[b][s*16+l] = sum_r inter[b][l][r] * w2[l][s][r] ----------------
// 1024 threads = 16 waves = 16 l; per wave: 64b x 64s tile (2x2 MFMA tiles, acc 64 regs).
// Plain full-unrolled K-loop: loads at top of each kstep, NO manual double-buffer --
// unified VGPR/AGPR budget is 128 for a 1024-thread block; manual prefetch forced
// ~145 live regs -> spill. Compiler pipelines within the budget.
// Epilogue: C transposed through 64KB LDS -> coalesced f32x4 stores, all 16 l per line.
__global__ __launch_bounds__(1024) void stage2_kernel(
    const short* __restrict__ interf, const short* __restrict__ w2f, float* __restrict__ out) {
  __shared__ float clds[16 * 1024];      // 64KB C-transpose buffer
  const int tid  = threadIdx.x;
  const int lane = tid & 63;
  const int l    = tid >> 6;             // wave = l
  const int lrow = lane & 31;
  const int khalf = lane >> 5;

  // grid decode: xcd owns A-quarter (8 BBT); 4bt x 4st supertiles (A+B ~4MB L2-resident)
  const int L    = blockIdx.x;           // 0..1023
  const int xcd  = L & 7;
  const int pos  = L >> 3;               // 0..127
  const int sup  = pos >> 4;             // 0..7
  const int inner = pos & 15;
  const int BBT  = xcd * 8 + (sup & 1) * 4 + (inner & 3);   // 0..63 (64 b-rows each)
  const int BST  = (sup >> 1) * 4 + (inner >> 2);           // 0..15 (64 s each)
  const int b0 = BBT * 64, s0 = BST * 64;

  // interf[btile][l][kstep][lane][8]: btile stride 131072, l stride 8192, kstep 512
  const short* ap = interf + (size_t)(BBT * 2) * 131072 + l * 8192 + lane * 8;
  // w2f[l][stile][kstep][lane][8]: l stride 262144, stile 8192, kstep 512
  const short* bp = w2f + (size_t)l * 262144 + (size_t)(BST * 2) * 8192 + lane * 8;

  f32x16 acc[2][2] = {};

  #pragma unroll
  for (int ks = 0; ks < 16; ++ks) {
    short8 a0 = *(const short8*)(ap + ks * 512);
    short8 a1 = *(const short8*)(ap + 131072 + ks * 512);
    short8 b0 = *(const short8*)(bp + ks * 512);
    short8 b1 = *(const short8*)(bp + 8192 + ks * 512);
    acc[0][0] = __builtin_amdgcn_mfma_f32_32x32x16_bf16(a0, b0, acc[0][0], 0, 0, 0);
    acc[0][1] = __builtin_amdgcn_mfma_f32_32x32x16_bf16(a0, b1, acc[0][1], 0, 0, 0);
    acc[1][0] = __builtin_amdgcn_mfma_f32_32x32x16_bf16(a1, b0, acc[1][0], 0, 0, 0);
    acc[1][1] = __builtin_amdgcn_mfma_f32_32x32x16_bf16(a1, b1, acc[1][1], 0, 0, 0);
  }

  // epilogue: 4 chunks of 16 rows; LDS [row16][col'] f32, col = scol*16 + l,
  // swizzle l-slot: l ^= ((scol&3)<<2) ^ (((row16>>2)&3)<<2)  (keeps f32x4 groups intact)
  #pragma unroll
  for (int c = 0; c < 4; ++c) {
    const int bt = c >> 1, rh = c & 1;
    #pragma unroll
    for (int st = 0; st < 2; ++st) {
      int scol = st * 32 + lrow;
      #pragma unroll
      for (int rr = 0; rr < 8; ++rr) {
        int row16 = (rr & 3) + 8 * (rr >> 2) + 4 * khalf;   // verified 32x32 C/D map (mod 16)
        int colx = scol * 16 + (l ^ ((scol & 3) << 2) ^ (((row16 >> 2) & 3) << 2));
        clds[row16 * 1024 + colx] = acc[bt][st][rh * 8 + rr];
      }
    }
    __syncthreads();
    #pragma unroll
    for (int p = 0; p < 4; ++p) {
      int idx  = p * 1024 + tid;
      int row  = idx >> 8;                 // 0..15
      int slot = idx & 255;
      int scol = slot >> 2, lq = slot & 3;
      int colx = scol * 16 + ((lq * 4) ^ ((scol & 3) << 2) ^ (((row >> 2) & 3) << 2));
      f32x4 v = *(const f32x4*)&clds[row * 1024 + colx];
      *(f32x4*)(out + (size_t)(b0 + c * 16 + row) * 16384
                     + (size_t)(s0 + scol) * 16 + lq * 4) = v;
    }
    __syncthreads();
  }
}

extern "C" void kernel_launch(void* const* d_in, const int* in_sizes, int n_in,
                              void* d_out, int out_size, void* d_ws, size_t ws_size,
                              hipStream_t stream) {
  const float* x  = (const float*)d_in[0];
  const float* w1 = (const float*)d_in[1];
  const float* w2 = (const float*)d_in[2];
  float* out = (float*)d_out;

  short* interf = (short*)d_ws;                          // 32 MB  (fragment-major)
  short* w1b    = (short*)((char*)d_ws + (32u << 20));   //  2 MB
  short* w2f    = (short*)((char*)d_ws + (34u << 20));   //  8 MB  (fragment-major)

  cvt_all<<<3072, 256, 0, stream>>>(w1, w1b, w2, w2f);
  stage1_kernel<<<dim3(64, 16), 256, 0, stream>>>(x, w1b, interf);
  stage2_kernel<<<1024, 1024, 0, stream>>>(interf, w2f, out);
}